// Round 5
// baseline (366.730 us; speedup 1.0000x reference)
//
#include <hip/hip_runtime.h>

// Problem constants (mirror the reference)
#define EMB      200000
#define DIM      256
#define WALK     80
#define WIN      5
#define BATCH    32
#define PPW      770                 // positive pairs per walk
#define NNEG     123200              // negative pairs
#define NPOSIT   2560                // BATCH*WALK node positions
#define LR       0.025f
#define LAP      0.01f
#define INV_STRIDE 64                // max 50 inverse hits per position

#define INV_BLOCKS  482              // ceil(NNEG/256)
#define OWN_BLOCKS  10               // ceil(NPOSIT/256)
#define GRAD_BLOCKS 1280             // 5120 waves: u-side + v-side per position
#define COPY_BLOCKS 2048             // 1024 per table

// zero region: cnt (NPOSIT ints) + accu/accv (2*NPOSIT*DIM floats), contiguous
#define ZERO_V4     ((NPOSIT * 4 + 2 * NPOSIT * DIM * 4) / 16)   // 328320 float4
#define ZERO_BLOCKS ((ZERO_V4 + 255) / 256)                      // 1283

typedef __attribute__((ext_vector_type(4))) float v4f;

__device__ __forceinline__ float wave_sum(float s) {
#pragma unroll
    for (int off = 32; off > 0; off >>= 1) s += __shfl_xor(s, off, 64);
    return s;
}

__device__ __forceinline__ float fast_sig(const float* __restrict__ t, float d) {
    float s = fminf(fmaxf(d, -6.0f), 6.0f);
    int idx = (int)floorf((s + 6.01f) / 0.01f);
    return t[idx];
}

// Zero cnt + acc buffers (5.25 MB). Replaces the pathological hipMemsetAsync
// (graph-captured fill ran at 22 GB/s ≈ 240 µs; this runs at HBM rate ≈ 2 µs).
__global__ void __launch_bounds__(256) k_zero(v4f* __restrict__ ws) {
    int i = blockIdx.x * 256 + threadIdx.x;
    if (i < ZERO_V4) ws[i] = (v4f){0.f, 0.f, 0.f, 0.f};
}

// Build inverse index of negv (blocks [0,INV_BLOCKS)) and duplicate-node owner
// map (blocks [INV_BLOCKS, +OWN_BLOCKS)). cnt zeroed by k_zero.
__global__ void k_prep(const int* __restrict__ negv,
                       const int* __restrict__ nodes,
                       int* __restrict__ cnt,
                       int* __restrict__ inv,
                       int* __restrict__ owner) {
    int bid = blockIdx.x;
    if (bid < INV_BLOCKS) {
        int m = bid * 256 + threadIdx.x;
        if (m < NNEG) {
            int p = negv[m];
            int slot = atomicAdd(&cnt[p], 1);
            inv[p * INV_STRIDE + slot] = m;
        }
    } else {
        int p = (bid - INV_BLOCKS) * 256 + threadIdx.x;
        if (p < NPOSIT) {
            int n = nodes[p];
            int j = 0;
            while (nodes[j] != n) ++j;   // terminates at j==p at latest
            owner[p] = j;                // min position sharing this node
        }
    }
}

// One wave per (position, side): compute grad and atomically accumulate into
// the owner position's acc row (workspace only; tables read directly — L2 is
// clean in this phase so rows cache on first touch).
__global__ void __launch_bounds__(256) k_grad(
        const int*   __restrict__ nodes,
        const float* __restrict__ uw,
        const float* __restrict__ vw,
        const float* __restrict__ table,
        const int*   __restrict__ negu,
        const int*   __restrict__ negv,
        const int*   __restrict__ cnt,
        const int*   __restrict__ inv,
        const int*   __restrict__ owner,
        float*       __restrict__ accu,
        float*       __restrict__ accv) {
    int wid  = blockIdx.x * 4 + (threadIdx.x >> 6);   // 0..5119
    int lane = threadIdx.x & 63;
    int side = wid >= NPOSIT;                         // 0: u-side, 1: v-side
    int p    = side ? wid - NPOSIT : wid;
    int b    = p / WALK;
    int i    = p - b * WALK;
    int col  = lane * 4;

    int jlo = (i - WIN < 0) ? 0 : i - WIN;
    int jhi = (i + WIN > WALK - 1) ? WALK - 1 : i + WIN;
    int node_p = nodes[p];

    if (!side) {
        // grad_u[p]: window pairs (u=p, v=q) + negatives where p is the center.
        const float4 mu = *(const float4*)&uw[(size_t)node_p * DIM + col];
        float gx = 0.f, gy = 0.f, gz = 0.f, gw = 0.f;

        for (int j = jlo; j <= jhi; ++j) {
            if (j == i) continue;
            int q = b * WALK + j;
            float4 qv = *(const float4*)&vw[(size_t)nodes[q] * DIM + col];
            float d1 = wave_sum(mu.x * qv.x + mu.y * qv.y + mu.z * qv.z + mu.w * qv.w);
            float s1 = 1.0f - fast_sig(table, d1);
            gx += s1 * qv.x + LAP * (qv.x - mu.x);
            gy += s1 * qv.y + LAP * (qv.y - mu.y);
            gz += s1 * qv.z + LAP * (qv.z - mu.z);
            gw += s1 * qv.w + LAP * (qv.w - mu.w);
        }

        int S = 0;
        for (int k = 0; k < i; ++k)
            S += (k < WIN ? k : WIN) + ((WALK - 1 - k) < WIN ? (WALK - 1 - k) : WIN);
        int ci = (i < WIN ? i : WIN) + ((WALK - 1 - i) < WIN ? (WALK - 1 - i) : WIN);
        int mstart = 5 * (PPW * b + S);
        int mcnt   = 5 * ci;
        for (int t = 0; t < mcnt; ++t) {
            int z = negv[mstart + t];
            float4 zv = *(const float4*)&vw[(size_t)nodes[z] * DIM + col];
            float d  = wave_sum(mu.x * zv.x + mu.y * zv.y + mu.z * zv.z + mu.w * zv.w);
            float ns = -fast_sig(table, d);
            gx += ns * zv.x; gy += ns * zv.y; gz += ns * zv.z; gw += ns * zv.w;
        }

        float* dst = &accu[(size_t)owner[p] * DIM + col];
        atomicAdd(dst + 0, gx);
        atomicAdd(dst + 1, gy);
        atomicAdd(dst + 2, gz);
        atomicAdd(dst + 3, gw);
    } else {
        // grad_v[p]: window pairs (u=q, v=p) + negatives where p is the v target.
        const float4 mv = *(const float4*)&vw[(size_t)node_p * DIM + col];
        float gx = 0.f, gy = 0.f, gz = 0.f, gw = 0.f;

        for (int j = jlo; j <= jhi; ++j) {
            if (j == i) continue;
            int q = b * WALK + j;
            float4 qu = *(const float4*)&uw[(size_t)nodes[q] * DIM + col];
            float d2 = wave_sum(qu.x * mv.x + qu.y * mv.y + qu.z * mv.z + qu.w * mv.w);
            float s2 = 1.0f - fast_sig(table, d2);
            gx += s2 * qu.x + LAP * (qu.x - mv.x);
            gy += s2 * qu.y + LAP * (qu.y - mv.y);
            gz += s2 * qu.z + LAP * (qu.z - mv.z);
            gw += s2 * qu.w + LAP * (qu.w - mv.w);
        }

        int ninv = cnt[p];
        for (int t = 0; t < ninv; ++t) {
            int m = inv[p * INV_STRIDE + t];
            int a = negu[m];
            float4 au = *(const float4*)&uw[(size_t)nodes[a] * DIM + col];
            float d  = wave_sum(au.x * mv.x + au.y * mv.y + au.z * mv.z + au.w * mv.w);
            float ns = -fast_sig(table, d);
            gx += ns * au.x; gy += ns * au.y; gz += ns * au.z; gw += ns * au.w;
        }

        float* dst = &accv[(size_t)owner[p] * DIM + col];
        atomicAdd(dst + 0, gx);
        atomicAdd(dst + 1, gy);
        atomicAdd(dst + 2, gz);
        atomicAdd(dst + 3, gw);
    }
}

// Bulk table copy with nontemporal hints (no L2 allocation for the stream).
__global__ void __launch_bounds__(256) k_copy(const float* __restrict__ uw,
                                              const float* __restrict__ vw,
                                              float* __restrict__ out) {
    const size_t T4 = (size_t)EMB * DIM / 4;          // float4 per table
    int cb  = blockIdx.x;
    int tbl = cb & 1;
    size_t blk = (size_t)(cb >> 1);                   // 0..1023
    const v4f* __restrict__ src = (const v4f*)(tbl ? vw : uw);
    v4f* __restrict__ dst = (v4f*)out + (size_t)tbl * T4;
    const size_t stride = (size_t)(COPY_BLOCKS / 2) * 256;
    for (size_t i = blk * 256 + threadIdx.x; i < T4; i += stride) {
        v4f v = __builtin_nontemporal_load(&src[i]);
        __builtin_nontemporal_store(v, &dst[i]);
    }
}

// Owner positions write their final rows: out = w + LR*acc (direct store).
__global__ void k_final(const int* __restrict__ nodes,
                        const float* __restrict__ uw,
                        const float* __restrict__ vw,
                        const float* __restrict__ accu,
                        const float* __restrict__ accv,
                        const int* __restrict__ owner,
                        float* __restrict__ out) {
    int p = blockIdx.x;
    if (owner[p] != p) return;        // duplicate node: owner writes once
    int d = threadIdx.x;
    int n = nodes[p];
    size_t off = (size_t)n * DIM + d;
    out[off] = uw[off] + LR * accu[(size_t)p * DIM + d];
    out[(size_t)EMB * DIM + off] = vw[off] + LR * accv[(size_t)p * DIM + d];
}

extern "C" void kernel_launch(void* const* d_in, const int* in_sizes, int n_in,
                              void* d_out, int out_size, void* d_ws, size_t ws_size,
                              hipStream_t stream) {
    const int*   nodes = (const int*)d_in[0];
    const float* uw    = (const float*)d_in[1];
    const float* vw    = (const float*)d_in[2];
    const float* table = (const float*)d_in[3];
    // d_in[4] = idx_posu, d_in[5] = idx_posv (window is analytic)
    const int*   negu  = (const int*)d_in[6];
    const int*   negv  = (const int*)d_in[7];
    float* out = (float*)d_out;

    // ws layout: [cnt | accu | accv | inv | owner]; first three zeroed per call.
    int*   cnt   = (int*)d_ws;
    float* accu  = (float*)(cnt + NPOSIT);
    float* accv  = accu + (size_t)NPOSIT * DIM;
    int*   inv   = (int*)(accv + (size_t)NPOSIT * DIM);
    int*   owner = inv + (size_t)NPOSIT * INV_STRIDE;

    k_zero<<<ZERO_BLOCKS, 256, 0, stream>>>((v4f*)d_ws);
    k_prep<<<INV_BLOCKS + OWN_BLOCKS, 256, 0, stream>>>(negv, nodes, cnt, inv, owner);
    k_grad<<<GRAD_BLOCKS, 256, 0, stream>>>(nodes, uw, vw, table, negu, negv,
                                            cnt, inv, owner, accu, accv);
    k_copy<<<COPY_BLOCKS, 256, 0, stream>>>(uw, vw, out);
    k_final<<<NPOSIT, DIM, 0, stream>>>(nodes, uw, vw, accu, accv, owner, out);
}

// Round 6
// 212.935 us; speedup vs baseline: 1.7223x; 1.7223x over previous
//
#include <hip/hip_runtime.h>

// Problem constants (mirror the reference)
#define EMB      200000
#define DIM      256
#define WALK     80
#define WIN      5
#define BATCH    32
#define PPW      770                 // positive pairs per walk
#define NPOSN    (BATCH * PPW)       // 24640 positive pairs
#define NNEG     (NPOSN * 5)         // 123200 negative pairs
#define NPOSIT   (BATCH * WALK)      // 2560 node positions
#define LR       0.025f
#define LAP      0.01f
#define INV_STRIDE 64                // max 50 inverse hits per position

#define GRAD_BLOCKS 1280             // 5120 waves: u-side + v-side per position
#define T4          (EMB * DIM / 4)  // 12,800,000 float4 per table
#define CHUNK_F4    2048             // 32 KB per copy block
#define COPY_CHUNKS (2 * T4 / CHUNK_F4)   // 12,500

__device__ __forceinline__ float wave_sum(float s) {
#pragma unroll
    for (int off = 32; off > 0; off >>= 1) s += __shfl_xor(s, off, 64);
    return s;
}

__device__ __forceinline__ float fast_sig(const float* __restrict__ t, float d) {
    float s = fminf(fmaxf(d, -6.0f), 6.0f);
    int idx = (int)floorf((s + 6.01f) / 0.01f);
    return t[idx];
}

// Gather the 2560 touched rows of each table into workspace; zero inverse counters.
__global__ void k_gather(const int* __restrict__ nodes,
                         const float* __restrict__ uw,
                         const float* __restrict__ vw,
                         float* __restrict__ eu,
                         float* __restrict__ ev,
                         int* __restrict__ cnt) {
    int p = blockIdx.x;
    int d = threadIdx.x;
    int node = nodes[p];
    eu[p * DIM + d] = uw[(size_t)node * DIM + d];
    ev[p * DIM + d] = vw[(size_t)node * DIM + d];
    if (d == 0) cnt[p] = 0;
}

// Build inverse index of idx_negv: for each position p, list of pair ids m with negv[m]==p.
__global__ void k_inv(const int* __restrict__ negv,
                      int* __restrict__ cnt,
                      int* __restrict__ inv) {
    int m = blockIdx.x * blockDim.x + threadIdx.x;
    if (m >= NNEG) return;
    int p = negv[m];
    int slot = atomicAdd(&cnt[p], 1);
    inv[p * INV_STRIDE + slot] = m;
}

// Fused kernel:
//   blocks [0, GRAD_BLOCKS)              : gradient compute into gu/gv (ws only)
//   blocks [GRAD_BLOCKS, +COPY_CHUNKS)   : 819 MB table copy, 32 KB contiguous
//                                          chunk per block (short-lived blocks
//                                          churn; grad overlaps cleanly)
__global__ void __launch_bounds__(256) k_fused(
        const float* __restrict__ uw,
        const float* __restrict__ vw,
        const float* __restrict__ table,
        const int*   __restrict__ negu,
        const int*   __restrict__ negv,
        const float* __restrict__ eu,
        const float* __restrict__ ev,
        const int*   __restrict__ cnt,
        const int*   __restrict__ inv,
        float*       __restrict__ gu,
        float*       __restrict__ gv,
        float*       __restrict__ out) {
    if (blockIdx.x >= GRAD_BLOCKS) {
        // ---------------- copy chunk ----------------
        size_t base = (size_t)(blockIdx.x - GRAD_BLOCKS) * CHUNK_F4;   // global f4 idx
        const float4* __restrict__ src;
        size_t soff;
        if (base < (size_t)T4) { src = (const float4*)uw; soff = base; }
        else                   { src = (const float4*)vw; soff = base - T4; }
        float4* __restrict__ dst = (float4*)out + base;
        int t = threadIdx.x;
#pragma unroll
        for (int k = 0; k < CHUNK_F4 / 256; ++k)
            dst[t + k * 256] = src[soff + t + k * 256];
        return;
    }

    // ---------------- grad half ----------------
    int wid  = blockIdx.x * 4 + (threadIdx.x >> 6);    // 0..5119
    int lane = threadIdx.x & 63;
    int side = wid >= NPOSIT;                          // 0: u-side, 1: v-side
    int p    = side ? wid - NPOSIT : wid;
    int b    = p / WALK;
    int i    = p - b * WALK;

    int jlo = (i - WIN < 0) ? 0 : i - WIN;
    int jhi = (i + WIN > WALK - 1) ? WALK - 1 : i + WIN;

    if (!side) {
        // grad_u[p]: pairs (u=p, v=q) over window + negatives where p is center.
        const float4 mu = *(const float4*)&eu[p * DIM + lane * 4];
        float gx = 0.f, gy = 0.f, gz = 0.f, gw = 0.f;

        for (int j = jlo; j <= jhi; ++j) {
            if (j == i) continue;
            int q = b * WALK + j;
            float4 qv = *(const float4*)&ev[q * DIM + lane * 4];
            float d1 = wave_sum(mu.x * qv.x + mu.y * qv.y + mu.z * qv.z + mu.w * qv.w);
            float s1 = 1.0f - fast_sig(table, d1);
            gx += s1 * qv.x + LAP * (qv.x - mu.x);
            gy += s1 * qv.y + LAP * (qv.y - mu.y);
            gz += s1 * qv.z + LAP * (qv.z - mu.z);
            gw += s1 * qv.w + LAP * (qv.w - mu.w);
        }

        int S = 0;
        for (int k = 0; k < i; ++k)
            S += (k < WIN ? k : WIN) + ((WALK - 1 - k) < WIN ? (WALK - 1 - k) : WIN);
        int ci = (i < WIN ? i : WIN) + ((WALK - 1 - i) < WIN ? (WALK - 1 - i) : WIN);
        int mstart = 5 * (PPW * b + S);
        int mcnt   = 5 * ci;
        for (int t = 0; t < mcnt; ++t) {
            int z = negv[mstart + t];
            float4 zv = *(const float4*)&ev[z * DIM + lane * 4];
            float d  = wave_sum(mu.x * zv.x + mu.y * zv.y + mu.z * zv.z + mu.w * zv.w);
            float ns = -fast_sig(table, d);
            gx += ns * zv.x; gy += ns * zv.y; gz += ns * zv.z; gw += ns * zv.w;
        }
        *(float4*)&gu[p * DIM + lane * 4] = make_float4(gx, gy, gz, gw);
    } else {
        // grad_v[p]: pairs (u=q, v=p) over window + negatives where p is the v target.
        const float4 mv = *(const float4*)&ev[p * DIM + lane * 4];
        float gx = 0.f, gy = 0.f, gz = 0.f, gw = 0.f;

        for (int j = jlo; j <= jhi; ++j) {
            if (j == i) continue;
            int q = b * WALK + j;
            float4 qu = *(const float4*)&eu[q * DIM + lane * 4];
            float d2 = wave_sum(qu.x * mv.x + qu.y * mv.y + qu.z * mv.z + qu.w * mv.w);
            float s2 = 1.0f - fast_sig(table, d2);
            gx += s2 * qu.x + LAP * (qu.x - mv.x);
            gy += s2 * qu.y + LAP * (qu.y - mv.y);
            gz += s2 * qu.z + LAP * (qu.z - mv.z);
            gw += s2 * qu.w + LAP * (qu.w - mv.w);
        }

        int ninv = cnt[p];
        for (int t = 0; t < ninv; ++t) {
            int m = inv[p * INV_STRIDE + t];
            int a = negu[m];
            float4 au = *(const float4*)&eu[a * DIM + lane * 4];
            float d  = wave_sum(au.x * mv.x + au.y * mv.y + au.z * mv.z + au.w * mv.w);
            float ns = -fast_sig(table, d);
            gx += ns * au.x; gy += ns * au.y; gz += ns * au.z; gw += ns * au.w;
        }
        *(float4*)&gv[p * DIM + lane * 4] = make_float4(gx, gy, gz, gw);
    }
}

// Apply LR*grad into the copied output tables (atomic: flat may contain duplicate nodes).
__global__ void k_apply(const int* __restrict__ nodes,
                        const float* __restrict__ gu,
                        const float* __restrict__ gv,
                        float* __restrict__ out) {
    int p = blockIdx.x;
    int d = threadIdx.x;
    int node = nodes[p];
    atomicAdd(&out[(size_t)node * DIM + d],                 LR * gu[p * DIM + d]);
    atomicAdd(&out[((size_t)EMB + (size_t)node) * DIM + d], LR * gv[p * DIM + d]);
}

extern "C" void kernel_launch(void* const* d_in, const int* in_sizes, int n_in,
                              void* d_out, int out_size, void* d_ws, size_t ws_size,
                              hipStream_t stream) {
    const int*   nodes = (const int*)d_in[0];
    const float* uw    = (const float*)d_in[1];
    const float* vw    = (const float*)d_in[2];
    const float* table = (const float*)d_in[3];
    // d_in[4] = idx_posu, d_in[5] = idx_posv (window is analytic)
    const int*   negu  = (const int*)d_in[6];
    const int*   negv  = (const int*)d_in[7];
    float* out = (float*)d_out;

    float* eu  = (float*)d_ws;
    float* ev  = eu + (size_t)NPOSIT * DIM;
    float* gu  = ev + (size_t)NPOSIT * DIM;
    float* gv  = gu + (size_t)NPOSIT * DIM;
    int*   cnt = (int*)(gv + (size_t)NPOSIT * DIM);
    int*   inv = cnt + NPOSIT;

    // 1. Gather touched rows + zero counters.
    k_gather<<<NPOSIT, DIM, 0, stream>>>(nodes, uw, vw, eu, ev, cnt);
    // 2. Build inverse index of negv.
    k_inv<<<(NNEG + 255) / 256, 256, 0, stream>>>(negv, cnt, inv);
    // 3. Fused: grad compute (ws-only) overlapped with the chunked 819 MB copy.
    k_fused<<<GRAD_BLOCKS + COPY_CHUNKS, 256, 0, stream>>>(
        uw, vw, table, negu, negv, eu, ev, cnt, inv, gu, gv, out);
    // 4. Scatter LR*grad into out (handles duplicate node ids).
    k_apply<<<NPOSIT, DIM, 0, stream>>>(nodes, gu, gv, out);
}